// Round 8
// baseline (128.725 us; speedup 1.0000x reference)
//
#include <hip/hip_runtime.h>
#include <math.h>

#define NMELS   128
#define NFRAMES 626
#define NPAIRS  313
#define NBATCH  32
#define LSAMP   160000
#define NFREQ   513                         // 1024/2 + 1
#define PPB     2                           // frame-pairs per block (1 per wave)
#define NBLK    ((NPAIRS + PPB - 1) / PPB)  // 157
#define NCHUNK  NBLK                        // pcen chunk = 4 frames = 1 block

struct Bins { int v[NMELS + 2]; };          // 130 ints = 520 B kernarg

// reflect-pad index (np.pad mode='reflect', no edge repeat)
__device__ __forceinline__ int refl(int i) {
    if (i < 0) i = -i;
    else if (i >= LSAMP) i = 2 * LSAMP - 2 - i;
    return i;
}

__device__ __forceinline__ float2 cadd(float2 a, float2 b){return make_float2(a.x+b.x, a.y+b.y);}
__device__ __forceinline__ float2 csub(float2 a, float2 b){return make_float2(a.x-b.x, a.y-b.y);}
__device__ __forceinline__ float2 cmul(float2 a, float2 b){
    return make_float2(fmaf(a.x,b.x,-a.y*b.y), fmaf(a.x,b.y,a.y*b.x));
}
__device__ __forceinline__ float2 cmulnegi(float2 a){return make_float2(a.y, -a.x);}   // a * (-i)

// 16-point DFT, natural order in/out, registers only (HW-verified R5-R7).
__device__ __forceinline__ void dft16(float2* z) {
    const float2 W1 = make_float2( 0.92387953251f, -0.38268343236f);
    const float2 W2 = make_float2( 0.70710678119f, -0.70710678119f);
    const float2 W3 = make_float2( 0.38268343236f, -0.92387953251f);
    const float2 W6 = make_float2(-0.70710678119f, -0.70710678119f);
    const float2 W9 = make_float2(-0.92387953251f,  0.38268343236f);
    float2 g[16];
    #pragma unroll
    for (int q = 0; q < 4; q++) {
        float2 t0=z[q], t1=z[4+q], t2=z[8+q], t3=z[12+q];
        float2 A=cadd(t0,t2), B=csub(t0,t2), C=cadd(t1,t3), D=csub(t1,t3);
        g[q]    = cadd(A,C);
        g[4+q]  = make_float2(B.x + D.y, B.y - D.x);
        g[8+q]  = csub(A,C);
        g[12+q] = make_float2(B.x - D.y, B.y + D.x);
    }
    g[4+1] =cmul(g[4+1], W1); g[4+2] =cmul(g[4+2], W2); g[4+3] =cmul(g[4+3], W3);
    g[8+1] =cmul(g[8+1], W2); g[8+2] =cmulnegi(g[8+2]); g[8+3] =cmul(g[8+3], W6);
    g[12+1]=cmul(g[12+1],W3); g[12+2]=cmul(g[12+2],W6);  g[12+3]=cmul(g[12+3],W9);
    #pragma unroll
    for (int r = 0; r < 4; r++) {
        float2 t0=g[4*r], t1=g[4*r+1], t2=g[4*r+2], t3=g[4*r+3];
        float2 A=cadd(t0,t2), B=csub(t0,t2), C=cadd(t1,t3), D=csub(t1,t3);
        z[r]    = cadd(A,C);
        z[r+4]  = make_float2(B.x + D.y, B.y - D.x);
        z[r+8]  = csub(A,C);
        z[r+12] = make_float2(B.x - D.y, B.y + D.x);
    }
}

// powers w^1..w^15 via log-depth build (depth 4 vs serial depth 15)
__device__ __forceinline__ void twpow(float2 w1, float2* tw) {
    tw[1] = w1;
    tw[2] = cmul(tw[1], tw[1]);
    tw[4] = cmul(tw[2], tw[2]);
    tw[8] = cmul(tw[4], tw[4]);
    tw[3] = cmul(tw[2], tw[1]);
    tw[5] = cmul(tw[4], tw[1]);
    tw[6] = cmul(tw[4], tw[2]);
    tw[7] = cmul(tw[4], tw[3]);
    #pragma unroll
    for (int k = 9; k < 16; k++) tw[k] = cmul(tw[8], tw[k-8]);
}

// DFT4 over bq; output order j: {A+C, B-iD, A-C, B+iD} (matches verified R6 stage 3)
__device__ __forceinline__ void dft4v(const float2* t, float2* Z) {
    float2 A=cadd(t[0],t[2]), B=csub(t[0],t[2]), C=cadd(t[1],t[3]), D=csub(t[1],t[3]);
    Z[0] = cadd(A,C);
    Z[1] = make_float2(B.x + D.y, B.y - D.x);
    Z[2] = csub(A,C);
    Z[3] = make_float2(B.x - D.y, B.y + D.x);
}

// two-for-one unpack + magnitudes for bin k given Zk = Z[k], Zn = Z[1024-k]
__device__ __forceinline__ void emitmag(float* spec, int k, float2 Zk, float2 Zn) {
    float ar = Zk.x + Zn.x, ai = Zk.y - Zn.y;
    float br = Zk.y + Zn.y, bi = Zn.x - Zk.x;
    spec[k]         = 0.5f * sqrtf(ar*ar + ai*ai);
    spec[NFREQ + k] = 0.5f * sqrtf(br*br + bi*bi);
}

// 128-thread block = 2 wave-private FFT frame-pairs = 4 frames = 1 pcen chunk.
// Per wave: four-step 1024 = 16x16x4 FFT, 16 pts/lane in regs, in-place LDS
// exchanges in the wave's OWN 8704 B buffer -> no __syncthreads in FFT path.
// Stage 3 fused with unpack via mirror-column pairs: magnitudes computed in
// registers, no stage-3 LDS writeback. spec aliases buf (all 16 stage-3 reads
// are register-staged BEFORE any spec write; in-order per-wave DS pipe).
// LDS = 17.4 KB/block -> 9 blocks/CU.
__global__ __launch_bounds__(128, 4)
void fft_mel_kernel(const float* __restrict__ x, float* __restrict__ mel,
                    float* __restrict__ S, Bins bins) {
    __shared__ float2 wbuf[PPB][1088];      // 17408 B total

    const int tid = threadIdx.x;
    const int w   = tid >> 6;               // wave slot = pair-in-block
    const int u   = tid & 63;
    const int P   = blockIdx.x;             // chunk id 0..156
    const int b   = blockIdx.y;
    const int p   = P * PPB + w;            // global frame-pair

    float acc[4];                           // this lane's 4 mel outputs

    if (p < NPAIRS) {
        float2* buf  = wbuf[w];
        float*  spec = (float*)&wbuf[w][0]; // aliases buf (ordering handled below)

        // ---- load frame pair: z[n] = fr0[n] + i*fr1[n], fr0 = x[base..],
        //      fr1 = x[base+256..]. Interior blocks (311 of 313): float4 path.
        const float* xb = x + (size_t)b * LSAMP;
        const int base = 512 * p - 512;
        if (base >= 0 && base + 1280 <= LSAMP) {
            const float4* xv4 = (const float4*)(xb + base);
            #pragma unroll
            for (int j = 0; j < 4; j++) {
                float4 v0 = xv4[64*j + u];
                float4 v1 = xv4[64*j + u + 64];
                const int i = 4 * (64*j + u);
                buf[i]   = make_float2(v0.x, v1.x);
                buf[i+1] = make_float2(v0.y, v1.y);
                buf[i+2] = make_float2(v0.z, v1.z);
                buf[i+3] = make_float2(v0.w, v1.w);
            }
        } else {
            #pragma unroll
            for (int j = 0; j < 16; j++) {
                const int i = 64 * j + u;
                buf[i] = make_float2(xb[refl(base + i)], xb[refl(base + i + 256)]);
            }
        }

        float2 z[16], tw[16];

        // ---- stage 1: DFT16 over a of z[64a+u], twiddle W_1024^{u*k}, store 17u+k
        #pragma unroll
        for (int a = 0; a < 16; a++) z[a] = buf[64*a + u];
        dft16(z);
        {
            float s, c; __sincosf(-(float)M_PI * (float)u * (1.0f/512.0f), &s, &c);
            twpow(make_float2(c, s), tw);
            #pragma unroll
            for (int k = 1; k < 16; k++) z[k] = cmul(z[k], tw[k]);
        }
        #pragma unroll
        for (int k = 0; k < 16; k++) buf[17*u + k] = z[k];

        // ---- stage 2: u -> (k1=u>>2, bp=u&3); DFT16, twiddle W_64^{bp*k}
        const int k1 = u >> 2, bp = u & 3;
        #pragma unroll
        for (int a = 0; a < 16; a++) z[a] = buf[68*a + 17*bp + k1];
        dft16(z);
        {
            float s, c; __sincosf(-(float)M_PI * (float)bp * (1.0f/32.0f), &s, &c);
            twpow(make_float2(c, s), tw);
            #pragma unroll
            for (int k = 1; k < 16; k++) z[k] = cmul(z[k], tw[k]);
        }
        #pragma unroll
        for (int k = 0; k < 16; k++) buf[68*k + 17*bp + k1] = z[k];

        // ---- stage 3 fused with unpack: mirror-column pairs.
        // Column c (= kk1 + 16*k2a) holds its DFT4 inputs at 68*k2a + 17*bq + kk1;
        // outputs are X[c + 256*j]. Pairing c with 256-c gives Z[k] and Z[1024-k]
        // in-lane. Lane 0 takes self-paired cols {0, 128} + Nyquist bin 512.
        // ALL 16 reads are staged before ANY spec write (spec aliases buf).
        const int cA0 = u;
        const int cB0 = (u == 0) ? 128 : 256 - u;
        const int cA1 = 64 + u;
        const int cB1 = 192 - u;
        float2 tA0[4], tB0[4], tA1[4], tB1[4];
        #pragma unroll
        for (int bq = 0; bq < 4; bq++) {
            tA0[bq] = buf[68*(cA0 >> 4) + 17*bq + (cA0 & 15)];
            tB0[bq] = buf[68*(cB0 >> 4) + 17*bq + (cB0 & 15)];
            tA1[bq] = buf[68*(cA1 >> 4) + 17*bq + (cA1 & 15)];
            tB1[bq] = buf[68*(cB1 >> 4) + 17*bq + (cB1 & 15)];
        }
        {
            float2 ZA[4], ZB[4];
            dft4v(tA0, ZA); dft4v(tB0, ZB);
            #pragma unroll
            for (int j = 0; j < 2; j++) {
                float2 znA = (u == 0) ? ZA[(4-j) & 3] : ZB[3-j];
                emitmag(spec, cA0 + 256*j, ZA[j], znA);
                float2 znB = (u == 0) ? ZB[3-j] : ZA[3-j];
                emitmag(spec, cB0 + 256*j, ZB[j], znB);
            }
            if (u == 0) emitmag(spec, 512, ZA[2], ZA[2]);  // Nyquist, self-mirror
            dft4v(tA1, ZA); dft4v(tB1, ZB);
            #pragma unroll
            for (int j = 0; j < 2; j++) {
                emitmag(spec, cA1 + 256*j, ZA[j], ZB[3-j]);
                emitmag(spec, cB1 + 256*j, ZB[j], ZA[3-j]);
            }
        }

        // ---- sparse mel (fb synthesized from bin edges); lane -> pf, 4 bands
        const int r = u & 31, pf = u >> 5;
        const float* sp = spec + pf * NFREQ;
        #pragma unroll
        for (int i = 0; i < 4; i++) {
            const int mm = 32*i + r;
            const int a = bins.v[mm], bb = bins.v[mm+1], c = bins.v[mm+2];
            float a0 = 0.f;
            if (bb > a) {
                float s = 0.f;
                for (int f = a; f < bb; f++) s = fmaf(sp[f], (float)(f - a), s);
                a0 += s / (float)(bb - a);
            }
            if (c > bb) {
                float s = 0.f;
                for (int f = bb; f < c; f++) s = fmaf(sp[f], (float)(c - f), s);
                a0 += s / (float)(c - bb);
            }
            acc[i] = a0;
            mel[((size_t)b * NFRAMES + 2*p + pf) * NMELS + mm] = a0;
        }
    }
    __syncthreads();                        // both waves done with their spec

    // stage mel into LDS (wave-1's buf region; dead post-barrier): 4x128 f32
    float* melst = (float*)&wbuf[1][0];
    if (p < NPAIRS) {
        const int r = u & 31, pf = u >> 5;
        const int fl = 2*w + pf;            // local frame 0..3
        #pragma unroll
        for (int i = 0; i < 4; i++) melst[fl*NMELS + 32*i + r] = acc[i];
    }
    __syncthreads();

    // pcen phase A: chunk EMA-from-zero (t=0 seeds exactly)
    {
        const int t0 = P * 4;
        const int nf = (NFRAMES - t0 < 4) ? NFRAMES - t0 : 4;
        float s = 0.f;
        for (int f = 0; f < nf; f++) {
            float v = melst[f*NMELS + tid];
            s = (t0 + f == 0) ? v : fmaf(0.975f, s, 0.025f * v);
        }
        S[((size_t)b * NCHUNK + P) * NMELS + tid] = s;
    }
}

// PCEN phase B: exclusive affine scan over 157 chunks per (b,m).
// M_out = D4*M_in + S_c with D4 = 0.975^4.
__global__ __launch_bounds__(256)
void pcen_scan(const float* __restrict__ S, float* __restrict__ Mstart) {
    const int idx = blockIdx.x * 256 + threadIdx.x;   // 0..4095
    const int m = idx & 127;
    const int b = idx >> 7;
    if (b >= NBATCH) return;

    float D4; { float d = 0.975f; d *= d; d *= d; D4 = d; }

    const size_t base = (size_t)b * NCHUNK * NMELS + m;
    float M = 0.f;
    #pragma unroll 8
    for (int c = 0; c < NCHUNK; c++) {
        Mstart[base + (size_t)c * NMELS] = M;
        M = fmaf(D4, M, S[base + (size_t)c * NMELS]);
    }
}

// PCEN phase C: block = (chunk c, batch b), 128 threads = m.
// Replay 4 frames from the exact chunk-entry state.
__global__ __launch_bounds__(128)
void pcen_out(const float* __restrict__ mel, const float* __restrict__ Mstart,
              float* __restrict__ out) {
    const int m = threadIdx.x;
    const int c = blockIdx.x;               // 0..156
    const int b = blockIdx.y;

    float M = Mstart[((size_t)b * NCHUNK + c) * NMELS + m];

    const int t0 = c * 4;
    const int tend = (t0 + 4 < NFRAMES) ? t0 + 4 : NFRAMES;
    const float* mp = mel + (size_t)b * NFRAMES * NMELS + m;
    float*       op = out + (size_t)b * NFRAMES * NMELS + m;
    #pragma unroll 4
    for (int t = t0; t < tend; t++) {
        float v = mp[(size_t)t * NMELS];
        M = (t == 0) ? v : fmaf(0.975f, M, 0.025f * v);
        float den = __powf(M + 1e-6f, 0.98f);
        op[(size_t)t * NMELS] = sqrtf(v / den + 2.0f) - 1.41421356237f;
    }
}

extern "C" void kernel_launch(void* const* d_in, const int* in_sizes, int n_in,
                              void* d_out, int out_size, void* d_ws, size_t ws_size,
                              hipStream_t stream) {
    const float* x  = (const float*)d_in[0];   // (32, 160000)
    float* out = (float*)d_out;                // (32, 626, 128)

    float* mel    = (float*)d_ws;                              // 32*626*128 f32
    float* S      = mel + (size_t)NBATCH * NFRAMES * NMELS;    // 32*157*128 f32
    float* Mstart = S   + (size_t)NBATCH * NCHUNK * NMELS;     // 32*157*128 f32

    // Host-side bin edges, replicating numpy exactly in double.
    Bins bins;
    {
        const double m_max = 2595.0 * log10(1.0 + 8000.0 / 700.0);
        const double step  = m_max / 129.0;
        for (int i = 0; i < NMELS + 2; i++) {
            double mv = (i == NMELS + 1) ? m_max : (double)i * step;
            double f  = 700.0 * (pow(10.0, mv / 2595.0) - 1.0);
            bins.v[i] = (int)floor((double)(NFREQ - 1) * 2.0 * f / 16000.0);
        }
    }

    dim3 grid1(NBLK, NBATCH);
    fft_mel_kernel<<<grid1, 128, 0, stream>>>(x, mel, S, bins);

    pcen_scan<<<(NBATCH * NMELS + 255) / 256, 256, 0, stream>>>(S, Mstart);

    dim3 grid3(NCHUNK, NBATCH);
    pcen_out<<<grid3, 128, 0, stream>>>(mel, Mstart, out);
}

// Round 9
// 123.058 us; speedup vs baseline: 1.0460x; 1.0460x over previous
//
#include <hip/hip_runtime.h>
#include <math.h>

#define NMELS   128
#define NFRAMES 626
#define NPAIRS  313
#define NBATCH  32
#define LSAMP   160000
#define NFREQ   513                         // 1024/2 + 1
#define PPB     2                           // frame-pairs per block (1 per wave)
#define NBLK    ((NPAIRS + PPB - 1) / PPB)  // 157
#define NCHUNK  NBLK                        // pcen chunk = 4 frames = 1 block

struct Bins { int v[NMELS + 2]; };          // 130 ints = 520 B kernarg

// reflect-pad index (np.pad mode='reflect', no edge repeat)
__device__ __forceinline__ int refl(int i) {
    if (i < 0) i = -i;
    else if (i >= LSAMP) i = 2 * LSAMP - 2 - i;
    return i;
}

__device__ __forceinline__ float2 cadd(float2 a, float2 b){return make_float2(a.x+b.x, a.y+b.y);}
__device__ __forceinline__ float2 csub(float2 a, float2 b){return make_float2(a.x-b.x, a.y-b.y);}
__device__ __forceinline__ float2 cmul(float2 a, float2 b){
    return make_float2(fmaf(a.x,b.x,-a.y*b.y), fmaf(a.x,b.y,a.y*b.x));
}
__device__ __forceinline__ float2 cmulnegi(float2 a){return make_float2(a.y, -a.x);}   // a * (-i)

// 16-point DFT, natural order in/out, registers only (HW-verified R5-R8).
__device__ __forceinline__ void dft16(float2* z) {
    const float2 W1 = make_float2( 0.92387953251f, -0.38268343236f);
    const float2 W2 = make_float2( 0.70710678119f, -0.70710678119f);
    const float2 W3 = make_float2( 0.38268343236f, -0.92387953251f);
    const float2 W6 = make_float2(-0.70710678119f, -0.70710678119f);
    const float2 W9 = make_float2(-0.92387953251f,  0.38268343236f);
    float2 g[16];
    #pragma unroll
    for (int q = 0; q < 4; q++) {
        float2 t0=z[q], t1=z[4+q], t2=z[8+q], t3=z[12+q];
        float2 A=cadd(t0,t2), B=csub(t0,t2), C=cadd(t1,t3), D=csub(t1,t3);
        g[q]    = cadd(A,C);
        g[4+q]  = make_float2(B.x + D.y, B.y - D.x);
        g[8+q]  = csub(A,C);
        g[12+q] = make_float2(B.x - D.y, B.y + D.x);
    }
    g[4+1] =cmul(g[4+1], W1); g[4+2] =cmul(g[4+2], W2); g[4+3] =cmul(g[4+3], W3);
    g[8+1] =cmul(g[8+1], W2); g[8+2] =cmulnegi(g[8+2]); g[8+3] =cmul(g[8+3], W6);
    g[12+1]=cmul(g[12+1],W3); g[12+2]=cmul(g[12+2],W6);  g[12+3]=cmul(g[12+3],W9);
    #pragma unroll
    for (int r = 0; r < 4; r++) {
        float2 t0=g[4*r], t1=g[4*r+1], t2=g[4*r+2], t3=g[4*r+3];
        float2 A=cadd(t0,t2), B=csub(t0,t2), C=cadd(t1,t3), D=csub(t1,t3);
        z[r]    = cadd(A,C);
        z[r+4]  = make_float2(B.x + D.y, B.y - D.x);
        z[r+8]  = csub(A,C);
        z[r+12] = make_float2(B.x - D.y, B.y + D.x);
    }
}

// powers w^1..w^15 via log-depth build (depth 4 vs serial depth 15)
__device__ __forceinline__ void twpow(float2 w1, float2* tw) {
    tw[1] = w1;
    tw[2] = cmul(tw[1], tw[1]);
    tw[4] = cmul(tw[2], tw[2]);
    tw[8] = cmul(tw[4], tw[4]);
    tw[3] = cmul(tw[2], tw[1]);
    tw[5] = cmul(tw[4], tw[1]);
    tw[6] = cmul(tw[4], tw[2]);
    tw[7] = cmul(tw[4], tw[3]);
    #pragma unroll
    for (int k = 9; k < 16; k++) tw[k] = cmul(tw[8], tw[k-8]);
}

// DFT4 over bq; output order j: {A+C, B-iD, A-C, B+iD}
__device__ __forceinline__ void dft4v(const float2* t, float2* Z) {
    float2 A=cadd(t[0],t[2]), B=csub(t[0],t[2]), C=cadd(t[1],t[3]), D=csub(t[1],t[3]);
    Z[0] = cadd(A,C);
    Z[1] = make_float2(B.x + D.y, B.y - D.x);
    Z[2] = csub(A,C);
    Z[3] = make_float2(B.x - D.y, B.y + D.x);
}

// two-for-one unpack + magnitudes for bin k given Zk = Z[k], Zn = Z[1024-k]
__device__ __forceinline__ void emitmag(float* spec, int k, float2 Zk, float2 Zn) {
    float ar = Zk.x + Zn.x, ai = Zk.y - Zn.y;
    float br = Zk.y + Zn.y, bi = Zn.x - Zk.x;
    spec[k]         = 0.5f * sqrtf(ar*ar + ai*ai);
    spec[NFREQ + k] = 0.5f * sqrtf(br*br + bi*bi);
}

// 128-thread block = 2 wave-private FFT frame-pairs = 4 frames = 1 pcen chunk.
// (unchanged from R8 — see R8 notes; LDS 17.4 KB -> 9 blocks/CU)
__global__ __launch_bounds__(128, 4)
void fft_mel_kernel(const float* __restrict__ x, float* __restrict__ mel,
                    float* __restrict__ S, Bins bins) {
    __shared__ float2 wbuf[PPB][1088];      // 17408 B total

    const int tid = threadIdx.x;
    const int w   = tid >> 6;               // wave slot = pair-in-block
    const int u   = tid & 63;
    const int P   = blockIdx.x;             // chunk id 0..156
    const int b   = blockIdx.y;
    const int p   = P * PPB + w;            // global frame-pair

    float acc[4];                           // this lane's 4 mel outputs

    if (p < NPAIRS) {
        float2* buf  = wbuf[w];
        float*  spec = (float*)&wbuf[w][0]; // aliases buf (ordering handled below)

        const float* xb = x + (size_t)b * LSAMP;
        const int base = 512 * p - 512;
        if (base >= 0 && base + 1280 <= LSAMP) {
            const float4* xv4 = (const float4*)(xb + base);
            #pragma unroll
            for (int j = 0; j < 4; j++) {
                float4 v0 = xv4[64*j + u];
                float4 v1 = xv4[64*j + u + 64];
                const int i = 4 * (64*j + u);
                buf[i]   = make_float2(v0.x, v1.x);
                buf[i+1] = make_float2(v0.y, v1.y);
                buf[i+2] = make_float2(v0.z, v1.z);
                buf[i+3] = make_float2(v0.w, v1.w);
            }
        } else {
            #pragma unroll
            for (int j = 0; j < 16; j++) {
                const int i = 64 * j + u;
                buf[i] = make_float2(xb[refl(base + i)], xb[refl(base + i + 256)]);
            }
        }

        float2 z[16], tw[16];

        // stage 1
        #pragma unroll
        for (int a = 0; a < 16; a++) z[a] = buf[64*a + u];
        dft16(z);
        {
            float s, c; __sincosf(-(float)M_PI * (float)u * (1.0f/512.0f), &s, &c);
            twpow(make_float2(c, s), tw);
            #pragma unroll
            for (int k = 1; k < 16; k++) z[k] = cmul(z[k], tw[k]);
        }
        #pragma unroll
        for (int k = 0; k < 16; k++) buf[17*u + k] = z[k];

        // stage 2
        const int k1 = u >> 2, bp = u & 3;
        #pragma unroll
        for (int a = 0; a < 16; a++) z[a] = buf[68*a + 17*bp + k1];
        dft16(z);
        {
            float s, c; __sincosf(-(float)M_PI * (float)bp * (1.0f/32.0f), &s, &c);
            twpow(make_float2(c, s), tw);
            #pragma unroll
            for (int k = 1; k < 16; k++) z[k] = cmul(z[k], tw[k]);
        }
        #pragma unroll
        for (int k = 0; k < 16; k++) buf[68*k + 17*bp + k1] = z[k];

        // stage 3 fused with unpack (mirror-column pairs); reads staged first
        const int cA0 = u;
        const int cB0 = (u == 0) ? 128 : 256 - u;
        const int cA1 = 64 + u;
        const int cB1 = 192 - u;
        float2 tA0[4], tB0[4], tA1[4], tB1[4];
        #pragma unroll
        for (int bq = 0; bq < 4; bq++) {
            tA0[bq] = buf[68*(cA0 >> 4) + 17*bq + (cA0 & 15)];
            tB0[bq] = buf[68*(cB0 >> 4) + 17*bq + (cB0 & 15)];
            tA1[bq] = buf[68*(cA1 >> 4) + 17*bq + (cA1 & 15)];
            tB1[bq] = buf[68*(cB1 >> 4) + 17*bq + (cB1 & 15)];
        }
        {
            float2 ZA[4], ZB[4];
            dft4v(tA0, ZA); dft4v(tB0, ZB);
            #pragma unroll
            for (int j = 0; j < 2; j++) {
                float2 znA = (u == 0) ? ZA[(4-j) & 3] : ZB[3-j];
                emitmag(spec, cA0 + 256*j, ZA[j], znA);
                float2 znB = (u == 0) ? ZB[3-j] : ZA[3-j];
                emitmag(spec, cB0 + 256*j, ZB[j], znB);
            }
            if (u == 0) emitmag(spec, 512, ZA[2], ZA[2]);  // Nyquist
            dft4v(tA1, ZA); dft4v(tB1, ZB);
            #pragma unroll
            for (int j = 0; j < 2; j++) {
                emitmag(spec, cA1 + 256*j, ZA[j], ZB[3-j]);
                emitmag(spec, cB1 + 256*j, ZB[j], ZA[3-j]);
            }
        }

        // sparse mel
        const int r = u & 31, pf = u >> 5;
        const float* sp = spec + pf * NFREQ;
        #pragma unroll
        for (int i = 0; i < 4; i++) {
            const int mm = 32*i + r;
            const int a = bins.v[mm], bb = bins.v[mm+1], c = bins.v[mm+2];
            float a0 = 0.f;
            if (bb > a) {
                float s = 0.f;
                for (int f = a; f < bb; f++) s = fmaf(sp[f], (float)(f - a), s);
                a0 += s / (float)(bb - a);
            }
            if (c > bb) {
                float s = 0.f;
                for (int f = bb; f < c; f++) s = fmaf(sp[f], (float)(c - f), s);
                a0 += s / (float)(c - bb);
            }
            acc[i] = a0;
            mel[((size_t)b * NFRAMES + 2*p + pf) * NMELS + mm] = a0;
        }
    }
    __syncthreads();

    // stage mel into LDS (wave-1's buf region; dead post-barrier): 4x128 f32
    float* melst = (float*)&wbuf[1][0];
    if (p < NPAIRS) {
        const int r = u & 31, pf = u >> 5;
        const int fl = 2*w + pf;
        #pragma unroll
        for (int i = 0; i < 4; i++) melst[fl*NMELS + 32*i + r] = acc[i];
    }
    __syncthreads();

    // pcen phase A: chunk EMA-from-zero (t=0 seeds exactly)
    {
        const int t0 = P * 4;
        const int nf = (NFRAMES - t0 < 4) ? NFRAMES - t0 : 4;
        float s = 0.f;
        for (int f = 0; f < nf; f++) {
            float v = melst[f*NMELS + tid];
            s = (t0 + f == 0) ? v : fmaf(0.975f, s, 0.025f * v);
        }
        S[((size_t)b * NCHUNK + P) * NMELS + tid] = s;
    }
}

// PCEN phase B: wave-parallel affine scan. One WAVE per (b,m) sequence.
// Chunk decay is the constant D4 = 0.975^4, so Mstart(c) = sum_{j<c} D4^(c-1-j) S_j.
// Lane l owns chunks 3l..3l+2 (157 padded to 192): local combine (depth 2),
// 6-step shfl_up Hillis-Steele scan with scale D12^s, then reconstruct.
__global__ __launch_bounds__(256)
void pcen_scan(const float* __restrict__ S, float* __restrict__ Mstart) {
    const int tid  = threadIdx.x;
    const int lane = tid & 63;
    const int wid  = blockIdx.x * 4 + (tid >> 6);   // 0..4095 sequence id
    const int m = wid & 127;
    const int b = wid >> 7;

    const float D4  = 0.975f * 0.975f * 0.975f * 0.975f;
    const float D12 = D4 * D4 * D4;

    const size_t base = (size_t)b * NCHUNK * NMELS + m;
    const int c0 = 3 * lane;
    float s0 = (c0     < NCHUNK) ? S[base + (size_t)(c0    ) * NMELS] : 0.f;
    float s1 = (c0 + 1 < NCHUNK) ? S[base + (size_t)(c0 + 1) * NMELS] : 0.f;
    float s2 = (c0 + 2 < NCHUNK) ? S[base + (size_t)(c0 + 2) * NMELS] : 0.f;

    // lane-inclusive combination of its 3 chunks
    float X = fmaf(D4, fmaf(D4, s0, s1), s2);

    // wave-inclusive weighted scan: X_l = sum_{j<=l} D12^(l-j) T_j
    float w = D12;
    #pragma unroll
    for (int s = 1; s < 64; s <<= 1) {
        float y = __shfl_up(X, s, 64);
        if (lane >= s) X = fmaf(w, y, X);
        w = w * w;
    }
    // exclusive: M entering chunk 3l
    float E = __shfl_up(X, 1, 64);
    if (lane == 0) E = 0.f;

    float M0 = E;
    float M1 = fmaf(D4, M0, s0);
    float M2 = fmaf(D4, M1, s1);
    if (c0     < NCHUNK) Mstart[base + (size_t)(c0    ) * NMELS] = M0;
    if (c0 + 1 < NCHUNK) Mstart[base + (size_t)(c0 + 1) * NMELS] = M1;
    if (c0 + 2 < NCHUNK) Mstart[base + (size_t)(c0 + 2) * NMELS] = M2;
}

// PCEN phase C: block = (chunk c, batch b), 128 threads = m. (unchanged)
__global__ __launch_bounds__(128)
void pcen_out(const float* __restrict__ mel, const float* __restrict__ Mstart,
              float* __restrict__ out) {
    const int m = threadIdx.x;
    const int c = blockIdx.x;               // 0..156
    const int b = blockIdx.y;

    float M = Mstart[((size_t)b * NCHUNK + c) * NMELS + m];

    const int t0 = c * 4;
    const int tend = (t0 + 4 < NFRAMES) ? t0 + 4 : NFRAMES;
    const float* mp = mel + (size_t)b * NFRAMES * NMELS + m;
    float*       op = out + (size_t)b * NFRAMES * NMELS + m;
    #pragma unroll 4
    for (int t = t0; t < tend; t++) {
        float v = mp[(size_t)t * NMELS];
        M = (t == 0) ? v : fmaf(0.975f, M, 0.025f * v);
        float den = __powf(M + 1e-6f, 0.98f);
        op[(size_t)t * NMELS] = sqrtf(v / den + 2.0f) - 1.41421356237f;
    }
}

extern "C" void kernel_launch(void* const* d_in, const int* in_sizes, int n_in,
                              void* d_out, int out_size, void* d_ws, size_t ws_size,
                              hipStream_t stream) {
    const float* x  = (const float*)d_in[0];   // (32, 160000)
    float* out = (float*)d_out;                // (32, 626, 128)

    float* mel    = (float*)d_ws;                              // 32*626*128 f32
    float* S      = mel + (size_t)NBATCH * NFRAMES * NMELS;    // 32*157*128 f32
    float* Mstart = S   + (size_t)NBATCH * NCHUNK * NMELS;     // 32*157*128 f32

    // Host-side bin edges, replicating numpy exactly in double.
    Bins bins;
    {
        const double m_max = 2595.0 * log10(1.0 + 8000.0 / 700.0);
        const double step  = m_max / 129.0;
        for (int i = 0; i < NMELS + 2; i++) {
            double mv = (i == NMELS + 1) ? m_max : (double)i * step;
            double f  = 700.0 * (pow(10.0, mv / 2595.0) - 1.0);
            bins.v[i] = (int)floor((double)(NFREQ - 1) * 2.0 * f / 16000.0);
        }
    }

    dim3 grid1(NBLK, NBATCH);
    fft_mel_kernel<<<grid1, 128, 0, stream>>>(x, mel, S, bins);

    pcen_scan<<<1024, 256, 0, stream>>>(S, Mstart);

    dim3 grid3(NCHUNK, NBATCH);
    pcen_out<<<grid3, 128, 0, stream>>>(mel, Mstart, out);
}